// Round 2
// 244.705 us; speedup vs baseline: 1.0374x; 1.0374x over previous
//
#include <hip/hip_runtime.h>

#define SS 1024
#define BB 128
#define HH 1024
#define LL 2
#define DD 2048
#define NROWS (SS*BB)            // 131072 (t,b) rows
#define TSEG 512                 // timesteps per segment (R12: 128 -> 512)
#define NSEG 2                   // R12: 8 -> 2 segments -> 4 dispatches total
#define ROWSEG (TSEG*BB)         // 65536 rows per segment
#define RPW 8                    // rows per wave (ROWSEG / 8192)
#define NSCANB 16                // scanner blocks (8 batches each)
#define NWORKB 2048              // worker blocks (4 waves each -> 8192 waves)
#define L2E  1.4426950408889634f

// native vector type for nontemporal builtins (HIP_vector_type is rejected)
typedef float f32x4 __attribute__((ext_vector_type(4)));

__device__ __forceinline__ float fast_rcp(float x)  { return __builtin_amdgcn_rcpf(x); }
__device__ __forceinline__ float exp2_(float x)     { return __builtin_amdgcn_exp2f(x); }

// DPP quad_perm: CTRL = sel0|sel1<<2|sel2<<4|sel3<<6
template<int CTRL>
__device__ __forceinline__ float qperm(float x){
    return __int_as_float(__builtin_amdgcn_update_dpp(0, __float_as_int(x), CTRL, 0xF, 0xF, true));
}
// row_shr:4 (ctrl 0x114): dst lane i <- src lane i-4 within each row of 16.
// L1 lane (lb*8+4+g) receives L0 lane (lb*8+g) of the SAME batch.
__device__ __forceinline__ float rowshr4(float x){
    return __int_as_float(__builtin_amdgcn_update_dpp(0, __float_as_int(x), 0x114, 0xF, 0xF, true));
}

// R12/R13: 4-dispatch pipeline (was 10). Rationale: every phase is BW-bound
// (worker model: VALU ~3.2k cy/SIMD vs BW ~25.6k cy/CU) and measured
// effective BW was 4.06 TB/s vs 6.5 TB/s the fill kernels prove reachable
// -> the gap is per-dispatch ramp+drain bubbles (~8 us x 9 boundaries).
// Minimum dispatches for the dep chain k1 -> scan -> k3 with scan split
// in two halves is 4:
//   p0: k1(seg0) + weight-sums        (256 MB read)
//   p1: k1(seg1) || scan(seg0)        (256 MB read;  scan ~21-32 us hidden)
//   p2: k3(seg0) || scan(seg1)        (256 MB write)
//   p3: k3(seg1) + finals             (258 MB write)
// NO inter-block communication: all dependencies are between DISPATCHES.
__global__ __launch_bounds__(256) void fused_phase(
    const float* __restrict__ x, const float* __restrict__ W,
    const float* __restrict__ bias, float* out,
    float* __restrict__ s_out, float* __restrict__ finals,
    float* __restrict__ sums, float* __restrict__ state,
    int s1, int s2, int s3, int fin)
{
    float* pre = out + (size_t)NROWS * HH;   // hT/cT rows (2 MB) as pre scratch;
                                             // overwritten only by final-phase finals
    const int tid = threadIdx.x;

    if (blockIdx.x < NSCANB) {
        if (tid >= 64) return;
        const int lane = tid;

        if (s2 < 0) {
            // phase 0: compute 12 weight sums once (block 0 only)
            if (blockIdx.x == 0 && s1 == 0) {
                for (int s = 0; s < 12; ++s) {
                    const int base = (s < 4) ? s*DD
                                   : (s < 8) ? 4*DD + (s-4)*DD
                                             : 4*DD + (s-8)*DD + HH;
                    float v = 0.f;
                    #pragma unroll
                    for (int k = 0; k < 16; ++k) v += W[base + lane + k*64];
                    #pragma unroll
                    for (int off = 32; off >= 1; off >>= 1) v += __shfl_xor(v, off, 64);
                    if (lane == 0) sums[s] = v;
                }
            }
            return;
        }

        // ---------------- scan segment s2 ----------------
        const int gate = lane & 3;
        const int L    = (lane >> 2) & 1;
        const int lb   = lane >> 3;
        const int bb   = blockIdx.x * 8 + lb;

        const float sh = sums[L*4 + gate];       // sum W[L][g][0:H]
        const float sx = sums[8 + gate];         // sum W[1][g][H:2H]
        const float sc  = (gate == 1) ? (2.0f*L2E) : (-L2E);
        const float s_h = sh * sc;
        const float sxc = L ? sx * sc : 0.0f;
        const float pcc = L ? bias[4+gate] * sc : 0.0f;
        const float Ac  = (gate == 1) ? 1.0f : 0.0f;
        const float Bc  = (gate == 0) ? (2.0f*L2E) : ((gate == 1) ? -2.0f : 1.0f);

        const float* pbase = pre + ((size_t)bb << 12) + gate;   // + t*4
        float* obase = s_out + bb;

        const int t_lo = s2 * TSEG, t_hi = t_lo + TSEG;

        float h, cp, h0d1, h0d2;                 // cp = 2*L2E*c
        float4* st = (float4*)state + blockIdx.x*64 + lane;
        if (t_lo == 0) { h = 0.f; cp = 0.f; h0d1 = 0.f; h0d2 = 0.f; }
        else { float4 s = *st; h = s.x; cp = s.y; h0d1 = s.z; h0d2 = s.w; }

        constexpr int PF = 16;
        float buf[PF];
        #pragma unroll
        for (int u = 0; u < PF; ++u) buf[u] = pbase[(size_t)(t_lo + u) * 4];

        for (int t0 = t_lo; t0 < t_hi; t0 += PF) {
            #pragma unroll
            for (int u = 0; u < PF; ++u) {
                const int t = t0 + u;
                const float p = L ? pcc : buf[u];
                int tn = t + PF; if (tn > t_hi-1) tn = t_hi-1;   // stay in segment
                buf[u] = pbase[(size_t)tn * 4];

                const float P = fmaf(h0d2, sxc, p);      // L1 consumes h0_{t-2}
                const float g = fmaf(h, s_h, P);
                const float v = fmaf(Bc, fast_rcp(1.0f + exp2_(g)), Ac);
                const float w = v * qperm<0xB1>(v);
                const float cpn = fmaf(qperm<0xAA>(v), cp, qperm<0x00>(w));
                const float th = fmaf(-2.0f, fast_rcp(1.0f + exp2_(cpn)), 1.0f);
                const float hn = qperm<0xFF>(v) * th;
                // first 2 steps of each segment: L1 redoes steps already done by
                // the previous segment's flush (or spin-up at t=0) -> discard.
                const bool disc = (u < 2) && (t0 == t_lo) && L;
                h  = disc ? h  : hn;
                cp = disc ? cp : cpn;
                h0d2 = h0d1;
                h0d1 = rowshr4(h);                       // L0 h -> L1 quad (DPP)
                if (L && t >= t_lo + 2) obase[(size_t)(t-2) * BB] = h;
            }
        }

        const float h0f = h, c0f = cp;           // L0 finals (flush skips L0)

        // flush: 2 L1-only steps so rows [t_hi-2, t_hi) are written this phase
        #pragma unroll
        for (int fs = 0; fs < 2; ++fs) {
            const float p = L ? pcc : buf[0];
            const float P = fmaf(h0d2, sxc, p);
            const float g = fmaf(h, s_h, P);
            const float v = fmaf(Bc, fast_rcp(1.0f + exp2_(g)), Ac);
            const float w = v * qperm<0xB1>(v);
            const float cpn = fmaf(qperm<0xAA>(v), cp, qperm<0x00>(w));
            const float th = fmaf(-2.0f, fast_rcp(1.0f + exp2_(cpn)), 1.0f);
            const float hn = qperm<0xFF>(v) * th;
            if (L) { h = hn; cp = cpn; obase[(size_t)(t_hi-2+fs) * BB] = hn; }
            h0d2 = h0d1;
        }

        *st = make_float4(h, cp, h0d1, h0d2);    // state for next segment

        if (t_hi == SS && gate == 0) {
            if (L) { finals[128+bb] = h;   finals[384+bb] = cp  * (0.5f/L2E); }
            else   { finals[bb]     = h0f; finals[256+bb] = c0f * (0.5f/L2E); }
        }
        return;
    }

    // ---------------- BW worker ----------------
    const int lane = tid & 63;
    const int gw   = (blockIdx.x - NSCANB)*4 + (tid >> 6);   // 0..8191

    if (s1 >= 0) {
        // k1: RPW rows per wave of segment s1 -> transposed pre.
        // x is read exactly once -> nontemporal (skip L2 allocate).
        float4 wv[4][4];
        #pragma unroll
        for (int j = 0; j < 4; ++j)
            #pragma unroll
            for (int it = 0; it < 4; ++it)
                wv[j][it] = *(const float4*)(W + j*DD + HH + it*256 + lane*4);
        const float4 b0 = *(const float4*)(bias);

        #pragma unroll 2
        for (int j = 0; j < RPW; ++j) {
            const int row = s1*ROWSEG + gw*RPW + j;
            const float* xr = x + (size_t)row * HH;
            float a0 = 0.f, a1 = 0.f, a2 = 0.f, a3 = 0.f;
            #pragma unroll
            for (int it = 0; it < 4; ++it) {
                f32x4 xv = __builtin_nontemporal_load((const f32x4*)xr + it*64 + lane);
                a0 = fmaf(xv.x, wv[0][it].x, fmaf(xv.y, wv[0][it].y, fmaf(xv.z, wv[0][it].z, fmaf(xv.w, wv[0][it].w, a0))));
                a1 = fmaf(xv.x, wv[1][it].x, fmaf(xv.y, wv[1][it].y, fmaf(xv.z, wv[1][it].z, fmaf(xv.w, wv[1][it].w, a1))));
                a2 = fmaf(xv.x, wv[2][it].x, fmaf(xv.y, wv[2][it].y, fmaf(xv.z, wv[2][it].z, fmaf(xv.w, wv[2][it].w, a2))));
                a3 = fmaf(xv.x, wv[3][it].x, fmaf(xv.y, wv[3][it].y, fmaf(xv.z, wv[3][it].z, fmaf(xv.w, wv[3][it].w, a3))));
            }
            #pragma unroll
            for (int off = 32; off >= 1; off >>= 1) {
                a0 += __shfl_xor(a0, off, 64);
                a1 += __shfl_xor(a1, off, 64);
                a2 += __shfl_xor(a2, off, 64);
                a3 += __shfl_xor(a3, off, 64);
            }
            if (lane == 0) {
                float4 r = make_float4((a0 + b0.x) * (-L2E),
                                       (a1 + b0.y) * ( 2.0f * L2E),
                                       (a2 + b0.z) * (-L2E),
                                       (a3 + b0.w) * (-L2E));
                const int b = row & (BB-1), t = row >> 7;
                *(float4*)(pre + (((size_t)b << 10) + t) * 4) = r;
            }
        }
    }

    if (s3 >= 0) {
        // k3: broadcast RPW rows per wave of segment s3.
        // s_out rows are contiguous per wave -> 2 broadcast float4 loads.
        // out is written exactly once -> nontemporal stores.
        const int r0 = s3*ROWSEG + gw*RPW;
        const float4 v0 = *(const float4*)(s_out + r0);
        const float4 v1 = *(const float4*)(s_out + r0 + 4);
        const float vs[RPW] = {v0.x, v0.y, v0.z, v0.w, v1.x, v1.y, v1.z, v1.w};
        #pragma unroll
        for (int j = 0; j < RPW; ++j) {
            const f32x4 vv = {vs[j], vs[j], vs[j], vs[j]};
            f32x4* dst = (f32x4*)(out + (size_t)(r0 + j) * HH);
            #pragma unroll
            for (int it = 0; it < 4; ++it)
                __builtin_nontemporal_store(vv, dst + it*64 + lane);
        }
    }

    if (fin && gw < 512) {
        // finals: hT/cT rows (overwrites the pre region; scan is done)
        const float v = finals[gw];
        const f32x4 vv = {v, v, v, v};
        f32x4* dst = (f32x4*)(out + (size_t)(NROWS + gw) * HH);
        #pragma unroll
        for (int it = 0; it < 4; ++it)
            __builtin_nontemporal_store(vv, dst + it*64 + lane);
    }
}

extern "C" void kernel_launch(void* const* d_in, const int* in_sizes, int n_in,
                              void* d_out, int out_size, void* d_ws, size_t ws_size,
                              hipStream_t stream) {
    const float* x    = (const float*)d_in[0];   // [S,B,H]
    const float* W    = (const float*)d_in[1];   // [L,4,D]
    const float* bias = (const float*)d_in[2];   // [L,4]
    float* out = (float*)d_out;

    float* s_out  = (float*)d_ws;                // [131072]
    float* finals = s_out + NROWS;               // [512]
    float* sums   = finals + 512;                // [16]
    float* state  = sums + 16;                   // [16*64*4] floats (16B aligned)

    // 4-phase software pipeline: phase p = k1(p) || scan(p-1) || k3(p-2)
    for (int p = 0; p < 4; ++p) {
        const int a1 = (p <= 1) ? p : -1;
        const int a2 = (p >= 1 && p <= 2) ? p - 1 : -1;
        const int a3 = (p >= 2) ? p - 2 : -1;
        const int fn = (p == 3) ? 1 : 0;
        hipLaunchKernelGGL(fused_phase, dim3(NSCANB + NWORKB), dim3(256), 0, stream,
                           x, W, bias, out, s_out, finals, sums, state,
                           a1, a2, a3, fn);
    }
}

// Round 3
// 236.019 us; speedup vs baseline: 1.0755x; 1.0368x over previous
//
#include <hip/hip_runtime.h>

#define SS 1024
#define BB 128
#define HH 1024
#define LL 2
#define DD 2048
#define NROWS (SS*BB)            // 131072 (t,b) rows
#define TSEG 256                 // R14: 512 -> 256 (NSEG 2 -> 4, 6 dispatches)
#define NSEG 4
#define ROWSEG (TSEG*BB)         // 32768 rows per segment
#define RPW 4                    // rows per wave (ROWSEG / 8192)
#define NSCANB 16                // scanner blocks (8 batches each)
#define NWORKB 2048              // worker blocks (4 waves each -> 8192 waves)
#define L2E  1.4426950408889634f

// native vector type for nontemporal builtins (HIP_vector_type is rejected)
typedef float f32x4 __attribute__((ext_vector_type(4)));

__device__ __forceinline__ float fast_rcp(float x)  { return __builtin_amdgcn_rcpf(x); }
__device__ __forceinline__ float exp2_(float x)     { return __builtin_amdgcn_exp2f(x); }

// DPP quad_perm: CTRL = sel0|sel1<<2|sel2<<4|sel3<<6
template<int CTRL>
__device__ __forceinline__ float qperm(float x){
    return __int_as_float(__builtin_amdgcn_update_dpp(0, __float_as_int(x), CTRL, 0xF, 0xF, true));
}
// row_shr:4 (ctrl 0x114): dst lane i <- src lane i-4 within each row of 16.
// L1 lane (lb*8+4+g) receives L0 lane (lb*8+g) of the SAME batch.
__device__ __forceinline__ float rowshr4(float x){
    return __int_as_float(__builtin_amdgcn_update_dpp(0, __float_as_int(x), 0x114, 0xF, 0xF, true));
}

// R14: NSEG=4 (6 dispatches). R13's A/B showed 10->4 dispatches saved only
// 9 us: boundary cost is small, and TSEG=512 likely exposed the serial scan
// (per-step interval c ~300-400cy -> scan(512) ~65-85us > 41us worker read).
// NSEG=4 keeps scan/seg (~256c = 17-34us) hidden under worker phases while
// paying only 5 boundaries:
//   p0: k1(0)                 128 MB R
//   p1: k1(1) || scan(0)      128 MB R
//   p2: k1(2) || scan(1) || k3(0)   128R + 128W
//   p3: k1(3) || scan(2) || k3(1)   128R + 128W
//   p4: scan(3) || k3(2)      128 MB W
//   p5: k3(3) + finals        130 MB W
// NO inter-block communication: all dependencies are between DISPATCHES.
__global__ __launch_bounds__(256) void fused_phase(
    const float* __restrict__ x, const float* __restrict__ W,
    const float* __restrict__ bias, float* out,
    float* __restrict__ s_out, float* __restrict__ finals,
    float* __restrict__ sums, float* __restrict__ state,
    int s1, int s2, int s3, int fin)
{
    float* pre = out + (size_t)NROWS * HH;   // hT/cT rows (2 MB) as pre scratch;
                                             // overwritten only by final-phase finals
    const int tid = threadIdx.x;

    if (blockIdx.x < NSCANB) {
        if (tid >= 64) return;
        const int lane = tid;

        if (s2 < 0) {
            // phase 0: compute 12 weight sums once (block 0 only)
            if (blockIdx.x == 0 && s1 == 0) {
                for (int s = 0; s < 12; ++s) {
                    const int base = (s < 4) ? s*DD
                                   : (s < 8) ? 4*DD + (s-4)*DD
                                             : 4*DD + (s-8)*DD + HH;
                    float v = 0.f;
                    #pragma unroll
                    for (int k = 0; k < 16; ++k) v += W[base + lane + k*64];
                    #pragma unroll
                    for (int off = 32; off >= 1; off >>= 1) v += __shfl_xor(v, off, 64);
                    if (lane == 0) sums[s] = v;
                }
            }
            return;
        }

        // ---------------- scan segment s2 ----------------
        const int gate = lane & 3;
        const int L    = (lane >> 2) & 1;
        const int lb   = lane >> 3;
        const int bb   = blockIdx.x * 8 + lb;

        const float sh = sums[L*4 + gate];       // sum W[L][g][0:H]
        const float sx = sums[8 + gate];         // sum W[1][g][H:2H]
        const float sc  = (gate == 1) ? (2.0f*L2E) : (-L2E);
        const float s_h = sh * sc;
        const float sxc = L ? sx * sc : 0.0f;
        const float pcc = L ? bias[4+gate] * sc : 0.0f;
        const float Ac  = (gate == 1) ? 1.0f : 0.0f;
        const float Bc  = (gate == 0) ? (2.0f*L2E) : ((gate == 1) ? -2.0f : 1.0f);

        const float* pbase = pre + ((size_t)bb << 12) + gate;   // + t*4
        float* obase = s_out + bb;

        const int t_lo = s2 * TSEG, t_hi = t_lo + TSEG;

        float h, cp, h0d1, h0d2;                 // cp = 2*L2E*c
        float4* st = (float4*)state + blockIdx.x*64 + lane;
        if (t_lo == 0) { h = 0.f; cp = 0.f; h0d1 = 0.f; h0d2 = 0.f; }
        else { float4 s = *st; h = s.x; cp = s.y; h0d1 = s.z; h0d2 = s.w; }

        constexpr int PF = 16;
        float buf[PF];
        #pragma unroll
        for (int u = 0; u < PF; ++u) buf[u] = pbase[(size_t)(t_lo + u) * 4];

        for (int t0 = t_lo; t0 < t_hi; t0 += PF) {
            #pragma unroll
            for (int u = 0; u < PF; ++u) {
                const int t = t0 + u;
                const float p = L ? pcc : buf[u];
                int tn = t + PF; if (tn > t_hi-1) tn = t_hi-1;   // stay in segment
                buf[u] = pbase[(size_t)tn * 4];

                const float P = fmaf(h0d2, sxc, p);      // L1 consumes h0_{t-2}
                const float g = fmaf(h, s_h, P);
                const float v = fmaf(Bc, fast_rcp(1.0f + exp2_(g)), Ac);
                const float w = v * qperm<0xB1>(v);
                const float cpn = fmaf(qperm<0xAA>(v), cp, qperm<0x00>(w));
                const float th = fmaf(-2.0f, fast_rcp(1.0f + exp2_(cpn)), 1.0f);
                const float hn = qperm<0xFF>(v) * th;
                // first 2 steps of each segment: L1 redoes steps already done by
                // the previous segment's flush (or spin-up at t=0) -> discard.
                const bool disc = (u < 2) && (t0 == t_lo) && L;
                h  = disc ? h  : hn;
                cp = disc ? cp : cpn;
                h0d2 = h0d1;
                h0d1 = rowshr4(h);                       // L0 h -> L1 quad (DPP)
                if (L && t >= t_lo + 2) obase[(size_t)(t-2) * BB] = h;
            }
        }

        const float h0f = h, c0f = cp;           // L0 finals (flush skips L0)

        // flush: 2 L1-only steps so rows [t_hi-2, t_hi) are written this phase
        #pragma unroll
        for (int fs = 0; fs < 2; ++fs) {
            const float p = L ? pcc : buf[0];
            const float P = fmaf(h0d2, sxc, p);
            const float g = fmaf(h, s_h, P);
            const float v = fmaf(Bc, fast_rcp(1.0f + exp2_(g)), Ac);
            const float w = v * qperm<0xB1>(v);
            const float cpn = fmaf(qperm<0xAA>(v), cp, qperm<0x00>(w));
            const float th = fmaf(-2.0f, fast_rcp(1.0f + exp2_(cpn)), 1.0f);
            const float hn = qperm<0xFF>(v) * th;
            if (L) { h = hn; cp = cpn; obase[(size_t)(t_hi-2+fs) * BB] = hn; }
            h0d2 = h0d1;
        }

        *st = make_float4(h, cp, h0d1, h0d2);    // state for next segment

        if (t_hi == SS && gate == 0) {
            if (L) { finals[128+bb] = h;   finals[384+bb] = cp  * (0.5f/L2E); }
            else   { finals[bb]     = h0f; finals[256+bb] = c0f * (0.5f/L2E); }
        }
        return;
    }

    // ---------------- BW worker ----------------
    const int lane = tid & 63;
    const int gw   = (blockIdx.x - NSCANB)*4 + (tid >> 6);   // 0..8191

    if (s1 >= 0) {
        // k1: RPW rows per wave of segment s1 -> transposed pre.
        // x is read exactly once -> nontemporal (skip L2 allocate).
        float4 wv[4][4];
        #pragma unroll
        for (int j = 0; j < 4; ++j)
            #pragma unroll
            for (int it = 0; it < 4; ++it)
                wv[j][it] = *(const float4*)(W + j*DD + HH + it*256 + lane*4);
        const float4 b0 = *(const float4*)(bias);

        #pragma unroll 2
        for (int j = 0; j < RPW; ++j) {
            const int row = s1*ROWSEG + gw*RPW + j;
            const float* xr = x + (size_t)row * HH;
            float a0 = 0.f, a1 = 0.f, a2 = 0.f, a3 = 0.f;
            #pragma unroll
            for (int it = 0; it < 4; ++it) {
                f32x4 xv = __builtin_nontemporal_load((const f32x4*)xr + it*64 + lane);
                a0 = fmaf(xv.x, wv[0][it].x, fmaf(xv.y, wv[0][it].y, fmaf(xv.z, wv[0][it].z, fmaf(xv.w, wv[0][it].w, a0))));
                a1 = fmaf(xv.x, wv[1][it].x, fmaf(xv.y, wv[1][it].y, fmaf(xv.z, wv[1][it].z, fmaf(xv.w, wv[1][it].w, a1))));
                a2 = fmaf(xv.x, wv[2][it].x, fmaf(xv.y, wv[2][it].y, fmaf(xv.z, wv[2][it].z, fmaf(xv.w, wv[2][it].w, a2))));
                a3 = fmaf(xv.x, wv[3][it].x, fmaf(xv.y, wv[3][it].y, fmaf(xv.z, wv[3][it].z, fmaf(xv.w, wv[3][it].w, a3))));
            }
            #pragma unroll
            for (int off = 32; off >= 1; off >>= 1) {
                a0 += __shfl_xor(a0, off, 64);
                a1 += __shfl_xor(a1, off, 64);
                a2 += __shfl_xor(a2, off, 64);
                a3 += __shfl_xor(a3, off, 64);
            }
            if (lane == 0) {
                float4 r = make_float4((a0 + b0.x) * (-L2E),
                                       (a1 + b0.y) * ( 2.0f * L2E),
                                       (a2 + b0.z) * (-L2E),
                                       (a3 + b0.w) * (-L2E));
                const int b = row & (BB-1), t = row >> 7;
                *(float4*)(pre + (((size_t)b << 10) + t) * 4) = r;
            }
        }
    }

    if (s3 >= 0) {
        // k3: broadcast RPW rows per wave of segment s3.
        // s_out rows are contiguous per wave -> 1 broadcast float4 load.
        // out is written exactly once -> nontemporal stores.
        const int r0 = s3*ROWSEG + gw*RPW;
        const float4 v0 = *(const float4*)(s_out + r0);
        const float vs[RPW] = {v0.x, v0.y, v0.z, v0.w};
        #pragma unroll
        for (int j = 0; j < RPW; ++j) {
            const f32x4 vv = {vs[j], vs[j], vs[j], vs[j]};
            f32x4* dst = (f32x4*)(out + (size_t)(r0 + j) * HH);
            #pragma unroll
            for (int it = 0; it < 4; ++it)
                __builtin_nontemporal_store(vv, dst + it*64 + lane);
        }
    }

    if (fin && gw < 512) {
        // finals: hT/cT rows (overwrites the pre region; scan is done)
        const float v = finals[gw];
        const f32x4 vv = {v, v, v, v};
        f32x4* dst = (f32x4*)(out + (size_t)(NROWS + gw) * HH);
        #pragma unroll
        for (int it = 0; it < 4; ++it)
            __builtin_nontemporal_store(vv, dst + it*64 + lane);
    }
}

extern "C" void kernel_launch(void* const* d_in, const int* in_sizes, int n_in,
                              void* d_out, int out_size, void* d_ws, size_t ws_size,
                              hipStream_t stream) {
    const float* x    = (const float*)d_in[0];   // [S,B,H]
    const float* W    = (const float*)d_in[1];   // [L,4,D]
    const float* bias = (const float*)d_in[2];   // [L,4]
    float* out = (float*)d_out;

    float* s_out  = (float*)d_ws;                // [131072]
    float* finals = s_out + NROWS;               // [512]
    float* sums   = finals + 512;                // [16]
    float* state  = sums + 16;                   // [16*64*4] floats (16B aligned)

    // 6-phase software pipeline: phase p = k1(p) || scan(p-1) || k3(p-2)
    for (int p = 0; p < NSEG + 2; ++p) {
        const int a1 = (p <= NSEG - 1) ? p : -1;
        const int a2 = (p >= 1 && p <= NSEG) ? p - 1 : -1;
        const int a3 = (p >= 2) ? p - 2 : -1;
        const int fn = (p == NSEG + 1) ? 1 : 0;
        hipLaunchKernelGGL(fused_phase, dim3(NSCANB + NWORKB), dim3(256), 0, stream,
                           x, W, bias, out, s_out, finals, sums, state,
                           a1, a2, a3, fn);
    }
}